// Round 1
// 315.852 us; speedup vs baseline: 1.0469x; 1.0469x over previous
//
#include <hip/hip_runtime.h>
#include <hip/hip_bf16.h>

// Problem constants
#define HDIM   2880
#define NH     64
#define NKV    8
#define DHEAD  64
#define GQ     (NH / NKV)     // 8
#define WIN    128
#define NTOK   1024
#define QKV_N  ((NH + 2 * NKV) * DHEAD)   // 5120
#define QCOLS  (NH * DHEAD)               // 4096
#define KOFF   QCOLS                      // 4096
#define VOFF   (QCOLS + NKV * DHEAD)      // 4608

typedef __attribute__((ext_vector_type(8))) short short8;
typedef __attribute__((ext_vector_type(4))) float floatx4;

// Static device scratch (zero-init at module load).
__device__ unsigned short g_Xb   [(size_t)NTOK  * HDIM];          //  5.9 MB
__device__ unsigned short g_qkvb [(size_t)NTOK  * QKV_N];         // 10.5 MB bf16 qkv (post-rope)
__device__ unsigned short g_attn [(size_t)NTOK  * QCOLS];         //  8.4 MB
__device__ unsigned short g_WqkvT[(size_t)QKV_N * HDIM];          // 29.5 MB
__device__ unsigned short g_WoT  [(size_t)HDIM * QCOLS];          // 23.6 MB

__device__ __forceinline__ unsigned short f2b(float f) {
    __hip_bfloat16 h = __float2bfloat16(f);
    return *reinterpret_cast<unsigned short*>(&h);
}

__device__ __forceinline__ void gload_lds16(const unsigned short* g, unsigned short* l) {
    __builtin_amdgcn_global_load_lds(
        (const __attribute__((address_space(1))) unsigned int*)g,
        (__attribute__((address_space(3))) unsigned int*)l, 16, 0, 0);
}

// ---------------------------------------------------------------------------
// Fused transpose + f32->bf16 convert: in (K x N f32) -> out (N x K bf16).
// ---------------------------------------------------------------------------
__global__ __launch_bounds__(256) void transpose_cvt(
        const float* __restrict__ in, unsigned short* __restrict__ out,
        int K, int N) {
    int bk = blockIdx.x, bn = blockIdx.y;
    int t = threadIdx.x;
    __shared__ __align__(16) unsigned short T[64 * 72];
    #pragma unroll
    for (int i = 0; i < 4; ++i) {
        int c = i * 256 + t;          // float4 slots
        int r = c >> 4, cc = (c & 15) * 4;
        float4 v = *(const float4*)(in + (size_t)(bk * 64 + r) * N + bn * 64 + cc);
        T[r * 72 + cc + 0] = f2b(v.x);
        T[r * 72 + cc + 1] = f2b(v.y);
        T[r * 72 + cc + 2] = f2b(v.z);
        T[r * 72 + cc + 3] = f2b(v.w);
    }
    __syncthreads();
    #pragma unroll
    for (int i = 0; i < 2; ++i) {
        int c = i * 256 + t;
        int rn = c >> 3, kc = (c & 7) * 8;
        int4 vv;
        unsigned short* tp = (unsigned short*)&vv;
        #pragma unroll
        for (int j = 0; j < 8; ++j) tp[j] = T[(kc + j) * 72 + rn];
        *(int4*)(out + (size_t)(bn * 64 + rn) * K + bk * 64 + kc) = vv;
    }
}

// ---------------------------------------------------------------------------
// Elementwise f32 -> bf16 convert (for X).
// ---------------------------------------------------------------------------
__global__ __launch_bounds__(256) void cvt_bf16(
        const float* __restrict__ in, unsigned short* __restrict__ out, int n4) {
    int id = blockIdx.x * 256 + threadIdx.x;
    if (id >= n4) return;
    float4 v = *(const float4*)(in + (size_t)id * 4);
    ushort4 o;
    o.x = f2b(v.x); o.y = f2b(v.y); o.z = f2b(v.z); o.w = f2b(v.w);
    *(ushort4*)(out + (size_t)id * 4) = o;
}

// ---------------------------------------------------------------------------
// Direct full-K GEMM, 128x64 tile, BK=64, 4 waves stacked in M (each wave
// 32 rows x 64 cols, acc 2x4 of 16x16 frags). global_load_lds staging.
// XCD-aware bijective block swizzle (grid = 8*NBN, NBN col-tiles of 64).
// MODE 0: fused RoPE epilogue -> bf16 qkv (col tile == one head).
// MODE 1: plain f32 store to out (ld HDIM).
// ---------------------------------------------------------------------------
template<int KLEN, int MODE, int NBN>
__global__ __launch_bounds__(256) void gemm_dir(
        const unsigned short* __restrict__ A, const unsigned short* __restrict__ Bt,
        void* __restrict__ outp) {
    int d0 = blockIdx.x;                       // nwg = 8*NBN, nwg % 8 == 0
    int work = (d0 & 7) * NBN + (d0 >> 3);     // bijective XCD chunking
    int bm = work & 7, bn = work >> 3;         // 8 row tiles x NBN col tiles
    int t = threadIdx.x, lane = t & 63, wid = t >> 6;
    int quad = lane >> 4, ml = lane & 15;
    __shared__ __align__(16) unsigned short As[128 * 64];   // 16 KB
    __shared__ __align__(16) unsigned short Bs[64 * 64];    //  8 KB
    floatx4 acc[2][4];
    #pragma unroll
    for (int i = 0; i < 2; ++i)
        #pragma unroll
        for (int j = 0; j < 4; ++j) acc[i][j] = (floatx4){0.f, 0.f, 0.f, 0.f};

    int srow = lane >> 3;            // 0..7 within an 8-row group
    int scol = (lane & 7) * 8;       // 0..56
    const unsigned short* Ab = A  + (size_t)(bm * 128) * KLEN;
    const unsigned short* Bb = Bt + (size_t)(bn * 64) * KLEN;

    for (int k0 = 0; k0 < KLEN; k0 += 64) {
        #pragma unroll
        for (int j = 0; j < 4; ++j) {          // A: 16 groups of 8 rows
            int grp = wid * 4 + j;
            int r = grp * 8 + srow;
            gload_lds16(Ab + (size_t)r * KLEN + k0 + scol, &As[grp * 512]);
        }
        #pragma unroll
        for (int j = 0; j < 2; ++j) {          // B: 8 groups of 8 rows
            int grp = wid * 2 + j;
            int r = grp * 8 + srow;
            gload_lds16(Bb + (size_t)r * KLEN + k0 + scol, &Bs[grp * 512]);
        }
        __syncthreads();
        #pragma unroll
        for (int kk = 0; kk < 64; kk += 32) {
            short8 af[2], bf[4];
            #pragma unroll
            for (int mt = 0; mt < 2; ++mt)
                af[mt] = *(const short8*)&As[(wid * 32 + mt * 16 + ml) * 64 + kk + quad * 8];
            #pragma unroll
            for (int nt = 0; nt < 4; ++nt)
                bf[nt] = *(const short8*)&Bs[(nt * 16 + ml) * 64 + kk + quad * 8];
            #pragma unroll
            for (int mt = 0; mt < 2; ++mt)
                #pragma unroll
                for (int nt = 0; nt < 4; ++nt)
                    acc[mt][nt] = __builtin_amdgcn_mfma_f32_16x16x32_bf16(af[mt], bf[nt], acc[mt][nt], 0, 0, 0);
        }
        __syncthreads();
    }

    if constexpr (MODE == 0) {
        // col tile bn == head bn; heads 0..71 are q/k (RoPE), 72..79 are v.
        unsigned short* qp = (unsigned short*)outp;
        int cb = bn * 64;
        if (bn < NH + NKV) {
            // inv_freq for this lane's two d values (d = ml, d = 16+ml)
            float inv0 = expf(-(float)ml * 0.3724497053f);          // theta^(-d/32)
            float inv1 = expf(-(float)(16 + ml) * 0.3724497053f);
            #pragma unroll
            for (int mt = 0; mt < 2; ++mt) {
                #pragma unroll
                for (int r = 0; r < 4; ++r) {
                    int n = bm * 128 + wid * 32 + mt * 16 + quad * 4 + r;
                    unsigned short* op = qp + (size_t)n * QKV_N + cb;
                    float s0, c0, s1, c1;
                    sincosf((float)n * inv0, &s0, &c0);
                    sincosf((float)n * inv1, &s1, &c1);
                    float x1a = acc[mt][0][r], x2a = acc[mt][2][r];
                    float x1b = acc[mt][1][r], x2b = acc[mt][3][r];
                    op[ml]           = f2b(x1a * c0 - x2a * s0);
                    op[ml + 32]      = f2b(x2a * c0 + x1a * s0);
                    op[16 + ml]      = f2b(x1b * c1 - x2b * s1);
                    op[16 + ml + 32] = f2b(x2b * c1 + x1b * s1);
                }
            }
        } else {
            #pragma unroll
            for (int mt = 0; mt < 2; ++mt)
                #pragma unroll
                for (int r = 0; r < 4; ++r) {
                    int n = bm * 128 + wid * 32 + mt * 16 + quad * 4 + r;
                    unsigned short* op = qp + (size_t)n * QKV_N + cb;
                    #pragma unroll
                    for (int nt = 0; nt < 4; ++nt)
                        op[nt * 16 + ml] = f2b(acc[mt][nt][r]);
                }
        }
    } else {
        float* op0 = (float*)outp;
        #pragma unroll
        for (int mt = 0; mt < 2; ++mt)
            #pragma unroll
            for (int r = 0; r < 4; ++r) {
                int n = bm * 128 + wid * 32 + mt * 16 + quad * 4 + r;
                float* op = op0 + (size_t)n * HDIM + bn * 64;
                #pragma unroll
                for (int nt = 0; nt < 4; ++nt)
                    op[nt * 16 + ml] = acc[mt][nt][r];
            }
    }
}

// ---------------------------------------------------------------------------
// MFMA flash-style sliding-window attention with sinks, bf16 in/out.
// 1D grid 512 with XCD swizzle: each XCD owns one kv-head (K/V L2-resident).
// Block = (16-token Q-tile, kv-head); M = 8 heads x 16 tokens = 128 rows;
// wave w owns rows [w*32, w*32+32). Window rows [t0-127, t0+32] staged.
// ---------------------------------------------------------------------------
#define TQ     16
#define WROWS  160
#define KS_LD  72
#define VT_LD  168
#define PS_LD  168

__global__ __launch_bounds__(256) void attn_mfma(
        const unsigned short* __restrict__ qkvb,
        const float* __restrict__ sinks,
        unsigned short* __restrict__ aout) {
    int d0 = blockIdx.x;                       // 512 blocks
    int work = (d0 & 7) * 64 + (d0 >> 3);      // bijective: XCD x -> kh == x
    int t0 = (work & 63) * TQ, kh = work >> 6;
    int t = threadIdx.x, lane = t & 63, wid = t >> 6;
    int quad = lane >> 4, ml = lane & 15;
    int wavebase = wid * 32;

    __shared__ __align__(16) unsigned short Ks[WROWS * KS_LD];    // 22.5 KB
    __shared__ __align__(16) unsigned short Vt[DHEAD * VT_LD];    // 21   KB
    __shared__ __align__(16) unsigned short Ps[4 * 16 * PS_LD];   // 21   KB
    unsigned short* Psw = &Ps[wid * 16 * PS_LD];

    // ---- stage K (row-major) and V (transposed), straight bf16 copies
    #pragma unroll
    for (int i = 0; i < 5; ++i) {
        int c = i * 256 + t;              // 0..1279 ushort8 slots
        int w = c >> 3, d8 = (c & 7) * 8;
        int r = t0 - 127 + w;
        r = min(max(r, 0), NTOK - 1);
        *(int4*)&Ks[w * KS_LD + d8] =
            *(const int4*)(qkvb + (size_t)r * QKV_N + KOFF + kh * DHEAD + d8);
        int4 vv = *(const int4*)(qkvb + (size_t)r * QKV_N + VOFF + kh * DHEAD + d8);
        const unsigned short* vp = (const unsigned short*)&vv;
        #pragma unroll
        for (int j = 0; j < 8; ++j) Vt[(d8 + j) * VT_LD + w] = vp[j];
    }
    __syncthreads();

    // ---- Q A-fragments straight from global bf16
    short8 qf[2][2];
    #pragma unroll
    for (int mt = 0; mt < 2; ++mt) {
        int m = wavebase + mt * 16 + ml;
        int tl = m & 15, g = m >> 4;
        const unsigned short* qp = qkvb + (size_t)(t0 + tl) * QKV_N + (kh * GQ + g) * DHEAD;
        #pragma unroll
        for (int kk = 0; kk < 2; ++kk)
            qf[mt][kk] = *(const short8*)(qp + kk * 32 + quad * 8);
    }

    // ---- S = Q K^T  (this wave: 2 m-tiles x 10 n-tiles)
    floatx4 S[2][10];
    #pragma unroll
    for (int mt = 0; mt < 2; ++mt)
        #pragma unroll
        for (int nt = 0; nt < 10; ++nt) S[mt][nt] = (floatx4){0.f, 0.f, 0.f, 0.f};
    #pragma unroll
    for (int kk = 0; kk < 2; ++kk) {
        #pragma unroll
        for (int nt = 0; nt < 10; ++nt) {
            short8 kb = *(const short8*)&Ks[(nt * 16 + ml) * KS_LD + kk * 32 + quad * 8];
            #pragma unroll
            for (int mt = 0; mt < 2; ++mt)
                S[mt][nt] = __builtin_amdgcn_mfma_f32_16x16x32_bf16(qf[mt][kk], kb, S[mt][nt], 0, 0, 0);
        }
    }

    // ---- band mask + scale   (valid: w>=tl, w<=tl+127, w>=127-t0)
    int wmin0 = 127 - t0;
    #pragma unroll
    for (int mt = 0; mt < 2; ++mt) {
        #pragma unroll
        for (int r = 0; r < 4; ++r) {
            int tl = (wavebase + mt * 16 + quad * 4 + r) & 15;
            int wlo = tl > wmin0 ? tl : wmin0;
            int whi = tl + 127;
            #pragma unroll
            for (int nt = 0; nt < 10; ++nt) {
                int w = nt * 16 + ml;
                float s = S[mt][nt][r] * 0.125f;
                S[mt][nt][r] = (w >= wlo && w <= whi) ? s : -INFINITY;
            }
        }
    }

    // ---- softmax with sink (rows spread over 16 lanes of the quad)
    #pragma unroll
    for (int mt = 0; mt < 2; ++mt) {
        int g = (wavebase + mt * 16) >> 4;
        float sk = sinks[kh * GQ + g];
        #pragma unroll
        for (int r = 0; r < 4; ++r) {
            float rm = -INFINITY;
            #pragma unroll
            for (int nt = 0; nt < 10; ++nt) rm = fmaxf(rm, S[mt][nt][r]);
            #pragma unroll
            for (int off = 1; off < 16; off <<= 1) rm = fmaxf(rm, __shfl_xor(rm, off));
            rm = fmaxf(rm, sk);
            float sum = 0.f;
            #pragma unroll
            for (int nt = 0; nt < 10; ++nt) {
                float p = __expf(S[mt][nt][r] - rm);   // exp(-inf)=0 masks
                S[mt][nt][r] = p;
                sum += p;
            }
            #pragma unroll
            for (int off = 1; off < 16; off <<= 1) sum += __shfl_xor(sum, off);
            float inv = 1.f / (sum + __expf(sk - rm));
            #pragma unroll
            for (int nt = 0; nt < 10; ++nt) S[mt][nt][r] *= inv;
        }
    }

    // ---- PV one m-tile at a time through per-wave Ps (wave DS ops in-order)
    #pragma unroll
    for (int mt = 0; mt < 2; ++mt) {
        #pragma unroll
        for (int r = 0; r < 4; ++r) {
            int lr = quad * 4 + r;
            #pragma unroll
            for (int nt = 0; nt < 10; ++nt)
                Psw[lr * PS_LD + nt * 16 + ml] = f2b(S[mt][nt][r]);
        }
        floatx4 O[4];
        #pragma unroll
        for (int j = 0; j < 4; ++j) O[j] = (floatx4){0.f, 0.f, 0.f, 0.f};
        #pragma unroll
        for (int ks = 0; ks < 5; ++ks) {
            short8 pf = *(const short8*)&Psw[ml * PS_LD + ks * 32 + quad * 8];
            #pragma unroll
            for (int nt = 0; nt < 4; ++nt) {
                short8 vf = *(const short8*)&Vt[(nt * 16 + ml) * VT_LD + ks * 32 + quad * 8];
                O[nt] = __builtin_amdgcn_mfma_f32_16x16x32_bf16(pf, vf, O[nt], 0, 0, 0);
            }
        }
        #pragma unroll
        for (int r = 0; r < 4; ++r) {
            int mm = wavebase + mt * 16 + quad * 4 + r;
            int tl = mm & 15, g = mm >> 4;
            unsigned short* op = aout + (size_t)(t0 + tl) * QCOLS + (kh * GQ + g) * DHEAD;
            #pragma unroll
            for (int nt = 0; nt < 4; ++nt)
                op[nt * 16 + ml] = f2b(O[nt][r]);
        }
    }
}

// ---------------------------------------------------------------------------
extern "C" void kernel_launch(void* const* d_in, const int* in_sizes, int n_in,
                              void* d_out, int out_size, void* d_ws, size_t ws_size,
                              hipStream_t stream) {
    const float* X     = (const float*)d_in[0];  // 1024x2880 f32
    const float* Wqkv  = (const float*)d_in[1];  // 2880x5120 f32
    const float* Wo    = (const float*)d_in[2];  // 4096x2880 f32
    const float* sinks = (const float*)d_in[3];  // 64 f32
    float* out = (float*)d_out;                  // 1024x2880 f32

    unsigned short *Xb, *qkvb, *attn, *WqkvT, *WoT;
    hipGetSymbolAddress((void**)&Xb,    HIP_SYMBOL(g_Xb));
    hipGetSymbolAddress((void**)&qkvb,  HIP_SYMBOL(g_qkvb));
    hipGetSymbolAddress((void**)&attn,  HIP_SYMBOL(g_attn));
    hipGetSymbolAddress((void**)&WqkvT, HIP_SYMBOL(g_WqkvT));
    hipGetSymbolAddress((void**)&WoT,   HIP_SYMBOL(g_WoT));

    cvt_bf16<<<(NTOK * HDIM / 4 + 255) / 256, 256, 0, stream>>>(X, Xb, NTOK * HDIM / 4);
    transpose_cvt<<<dim3(HDIM / 64, QKV_N / 64), 256, 0, stream>>>(Wqkv, WqkvT, HDIM, QKV_N);
    transpose_cvt<<<dim3(QCOLS / 64, HDIM / 64), 256, 0, stream>>>(Wo, WoT, QCOLS, HDIM);

    // QKV projection, direct full-K, fused RoPE -> bf16 qkv
    gemm_dir<HDIM, 0, QKV_N / 64><<<8 * (QKV_N / 64), 256, 0, stream>>>(Xb, WqkvT, qkvb);

    // MFMA sliding-window attention -> bf16 attn
    attn_mfma<<<512, 256, 0, stream>>>(qkvb, sinks, attn);

    // Output projection, direct full-K -> f32 out
    gemm_dir<QCOLS, 1, HDIM / 64><<<8 * (HDIM / 64), 256, 0, stream>>>(attn, WoT, out);
}

// Round 2
// 311.984 us; speedup vs baseline: 1.0599x; 1.0124x over previous
//
#include <hip/hip_runtime.h>
#include <hip/hip_bf16.h>

// Problem constants
#define HDIM   2880
#define NH     64
#define NKV    8
#define DHEAD  64
#define GQ     (NH / NKV)     // 8
#define WIN    128
#define NTOK   1024
#define QKV_N  ((NH + 2 * NKV) * DHEAD)   // 5120
#define QCOLS  (NH * DHEAD)               // 4096
#define KOFF   QCOLS                      // 4096
#define VOFF   (QCOLS + NKV * DHEAD)      // 4608

typedef __attribute__((ext_vector_type(8))) short short8;
typedef __attribute__((ext_vector_type(4))) float floatx4;

// Static device scratch (zero-init at module load).
__device__ unsigned short g_Xb   [(size_t)NTOK  * HDIM];          //  5.9 MB
__device__ unsigned short g_qkvb [(size_t)NTOK  * QKV_N];         // 10.5 MB bf16 qkv (post-rope)
__device__ unsigned short g_attn [(size_t)NTOK  * QCOLS];         //  8.4 MB
__device__ unsigned short g_WqkvT[(size_t)QKV_N * HDIM];          // 29.5 MB
__device__ unsigned short g_WoT  [(size_t)HDIM * QCOLS];          // 23.6 MB

__device__ __forceinline__ unsigned short f2b(float f) {
    __hip_bfloat16 h = __float2bfloat16(f);
    return *reinterpret_cast<unsigned short*>(&h);
}

__device__ __forceinline__ void gload_lds16(const unsigned short* g, unsigned short* l) {
    __builtin_amdgcn_global_load_lds(
        (const __attribute__((address_space(1))) unsigned int*)g,
        (__attribute__((address_space(3))) unsigned int*)l, 16, 0, 0);
}

// ---------------------------------------------------------------------------
// Fused transpose + f32->bf16 convert: in (K x N f32) -> out (N x K bf16).
// ---------------------------------------------------------------------------
__global__ __launch_bounds__(256) void transpose_cvt(
        const float* __restrict__ in, unsigned short* __restrict__ out,
        int K, int N) {
    int bk = blockIdx.x, bn = blockIdx.y;
    int t = threadIdx.x;
    __shared__ __align__(16) unsigned short T[64 * 72];
    #pragma unroll
    for (int i = 0; i < 4; ++i) {
        int c = i * 256 + t;          // float4 slots
        int r = c >> 4, cc = (c & 15) * 4;
        float4 v = *(const float4*)(in + (size_t)(bk * 64 + r) * N + bn * 64 + cc);
        T[r * 72 + cc + 0] = f2b(v.x);
        T[r * 72 + cc + 1] = f2b(v.y);
        T[r * 72 + cc + 2] = f2b(v.z);
        T[r * 72 + cc + 3] = f2b(v.w);
    }
    __syncthreads();
    #pragma unroll
    for (int i = 0; i < 2; ++i) {
        int c = i * 256 + t;
        int rn = c >> 3, kc = (c & 7) * 8;
        int4 vv;
        unsigned short* tp = (unsigned short*)&vv;
        #pragma unroll
        for (int j = 0; j < 8; ++j) tp[j] = T[(kc + j) * 72 + rn];
        *(int4*)(out + (size_t)(bn * 64 + rn) * K + bk * 64 + kc) = vv;
    }
}

// ---------------------------------------------------------------------------
// Elementwise f32 -> bf16 convert (for X).
// ---------------------------------------------------------------------------
__global__ __launch_bounds__(256) void cvt_bf16(
        const float* __restrict__ in, unsigned short* __restrict__ out, int n4) {
    int id = blockIdx.x * 256 + threadIdx.x;
    if (id >= n4) return;
    float4 v = *(const float4*)(in + (size_t)id * 4);
    ushort4 o;
    o.x = f2b(v.x); o.y = f2b(v.y); o.z = f2b(v.z); o.w = f2b(v.w);
    *(ushort4*)(out + (size_t)id * 4) = o;
}

// ---------------------------------------------------------------------------
// Direct full-K GEMM, 128x64 tile, BK=64, 4 waves stacked in M (each wave
// 32 rows x 64 cols, acc 2x4 of 16x16 frags).
// 2-phase double-buffered pipeline: STAGE(next tile) issued before compute
// of current tile; single vmcnt(0)+barrier per K-step (T3-minimum).
// LDS XOR-swizzle: 16B unit u of row r stored at u^(r&7) — applied by
// inverse-permuting the global SOURCE address (global_load_lds dest must
// stay linear) and permuting the ds_read address identically.
// XCD-aware bijective block swizzle (grid = 8*NBN, NBN col-tiles of 64).
// MODE 0: fused RoPE epilogue -> bf16 qkv (col tile == one head).
// MODE 1: plain f32 store to out (ld HDIM).
// ---------------------------------------------------------------------------
template<int KLEN, int MODE, int NBN>
__global__ __launch_bounds__(256) void gemm_dir(
        const unsigned short* __restrict__ A, const unsigned short* __restrict__ Bt,
        void* __restrict__ outp) {
    int d0 = blockIdx.x;                       // nwg = 8*NBN, nwg % 8 == 0
    int work = (d0 & 7) * NBN + (d0 >> 3);     // bijective XCD chunking
    int bm = work & 7, bn = work >> 3;         // 8 row tiles x NBN col tiles
    int t = threadIdx.x, lane = t & 63, wid = t >> 6;
    int quad = lane >> 4, ml = lane & 15;
    __shared__ __align__(16) unsigned short As[2][128 * 64];   // 2 x 16 KB
    __shared__ __align__(16) unsigned short Bs[2][64 * 64];    // 2 x  8 KB
    floatx4 acc[2][4];
    #pragma unroll
    for (int i = 0; i < 2; ++i)
        #pragma unroll
        for (int j = 0; j < 4; ++j) acc[i][j] = (floatx4){0.f, 0.f, 0.f, 0.f};

    int srow = lane >> 3;                      // 0..7 within an 8-row group
    int scol = ((lane & 7) ^ srow) * 8;        // inverse-swizzled source unit
    const unsigned short* Ab = A  + (size_t)(bm * 128) * KLEN;
    const unsigned short* Bb = Bt + (size_t)(bn * 64) * KLEN;

    constexpr int NT = KLEN / 64;

    // prologue: stage tile 0 into buffer 0
    #pragma unroll
    for (int j = 0; j < 4; ++j) {
        int grp = wid * 4 + j;
        int r = grp * 8 + srow;
        gload_lds16(Ab + (size_t)r * KLEN + scol, &As[0][grp * 512]);
    }
    #pragma unroll
    for (int j = 0; j < 2; ++j) {
        int grp = wid * 2 + j;
        int r = grp * 8 + srow;
        gload_lds16(Bb + (size_t)r * KLEN + scol, &Bs[0][grp * 512]);
    }
    __syncthreads();

    for (int ti = 0; ti < NT; ++ti) {
        int cur = ti & 1;
        if (ti + 1 < NT) {                     // issue next-tile loads first
            int k0 = (ti + 1) * 64;
            int nxt = cur ^ 1;
            #pragma unroll
            for (int j = 0; j < 4; ++j) {
                int grp = wid * 4 + j;
                int r = grp * 8 + srow;
                gload_lds16(Ab + (size_t)r * KLEN + k0 + scol, &As[nxt][grp * 512]);
            }
            #pragma unroll
            for (int j = 0; j < 2; ++j) {
                int grp = wid * 2 + j;
                int r = grp * 8 + srow;
                gload_lds16(Bb + (size_t)r * KLEN + k0 + scol, &Bs[nxt][grp * 512]);
            }
        }
        #pragma unroll
        for (int kk = 0; kk < 64; kk += 32) {
            const int ub = kk >> 3;            // 0 or 4
            int usw = ((ub + quad) ^ (ml & 7)) * 8;
            short8 af[2], bf[4];
            #pragma unroll
            for (int mt = 0; mt < 2; ++mt)
                af[mt] = *(const short8*)&As[cur][(wid * 32 + mt * 16 + ml) * 64 + usw];
            #pragma unroll
            for (int nt = 0; nt < 4; ++nt)
                bf[nt] = *(const short8*)&Bs[cur][(nt * 16 + ml) * 64 + usw];
            #pragma unroll
            for (int mt = 0; mt < 2; ++mt)
                #pragma unroll
                for (int nt = 0; nt < 4; ++nt)
                    acc[mt][nt] = __builtin_amdgcn_mfma_f32_16x16x32_bf16(af[mt], bf[nt], acc[mt][nt], 0, 0, 0);
        }
        __syncthreads();   // drains this wave's vmcnt (next tile staged) + read fence
    }

    if constexpr (MODE == 0) {
        // col tile bn == head bn; heads 0..71 are q/k (RoPE), 72..79 are v.
        unsigned short* qp = (unsigned short*)outp;
        int cb = bn * 64;
        if (bn < NH + NKV) {
            // inv_freq for this lane's two d values (d = ml, d = 16+ml)
            float inv0 = expf(-(float)ml * 0.3724497053f);          // theta^(-d/32)
            float inv1 = expf(-(float)(16 + ml) * 0.3724497053f);
            #pragma unroll
            for (int mt = 0; mt < 2; ++mt) {
                #pragma unroll
                for (int r = 0; r < 4; ++r) {
                    int n = bm * 128 + wid * 32 + mt * 16 + quad * 4 + r;
                    unsigned short* op = qp + (size_t)n * QKV_N + cb;
                    float s0, c0, s1, c1;
                    sincosf((float)n * inv0, &s0, &c0);
                    sincosf((float)n * inv1, &s1, &c1);
                    float x1a = acc[mt][0][r], x2a = acc[mt][2][r];
                    float x1b = acc[mt][1][r], x2b = acc[mt][3][r];
                    op[ml]           = f2b(x1a * c0 - x2a * s0);
                    op[ml + 32]      = f2b(x2a * c0 + x1a * s0);
                    op[16 + ml]      = f2b(x1b * c1 - x2b * s1);
                    op[16 + ml + 32] = f2b(x2b * c1 + x1b * s1);
                }
            }
        } else {
            #pragma unroll
            for (int mt = 0; mt < 2; ++mt)
                #pragma unroll
                for (int r = 0; r < 4; ++r) {
                    int n = bm * 128 + wid * 32 + mt * 16 + quad * 4 + r;
                    unsigned short* op = qp + (size_t)n * QKV_N + cb;
                    #pragma unroll
                    for (int nt = 0; nt < 4; ++nt)
                        op[nt * 16 + ml] = f2b(acc[mt][nt][r]);
                }
        }
    } else {
        float* op0 = (float*)outp;
        #pragma unroll
        for (int mt = 0; mt < 2; ++mt)
            #pragma unroll
            for (int r = 0; r < 4; ++r) {
                int n = bm * 128 + wid * 32 + mt * 16 + quad * 4 + r;
                float* op = op0 + (size_t)n * HDIM + bn * 64;
                #pragma unroll
                for (int nt = 0; nt < 4; ++nt)
                    op[nt * 16 + ml] = acc[mt][nt][r];
            }
    }
}

// ---------------------------------------------------------------------------
// MFMA flash-style sliding-window attention with sinks, bf16 in/out.
// 1D grid 512 with XCD swizzle: each XCD owns one kv-head (K/V L2-resident).
// Block = (16-token Q-tile, kv-head); M = 8 heads x 16 tokens = 128 rows;
// wave w owns rows [w*32, w*32+32). Window rows [t0-127, t0+32] staged.
// ---------------------------------------------------------------------------
#define TQ     16
#define WROWS  160
#define KS_LD  72
#define VT_LD  168
#define PS_LD  168

__global__ __launch_bounds__(256) void attn_mfma(
        const unsigned short* __restrict__ qkvb,
        const float* __restrict__ sinks,
        unsigned short* __restrict__ aout) {
    int d0 = blockIdx.x;                       // 512 blocks
    int work = (d0 & 7) * 64 + (d0 >> 3);      // bijective: XCD x -> kh == x
    int t0 = (work & 63) * TQ, kh = work >> 6;
    int t = threadIdx.x, lane = t & 63, wid = t >> 6;
    int quad = lane >> 4, ml = lane & 15;
    int wavebase = wid * 32;

    __shared__ __align__(16) unsigned short Ks[WROWS * KS_LD];    // 22.5 KB
    __shared__ __align__(16) unsigned short Vt[DHEAD * VT_LD];    // 21   KB
    __shared__ __align__(16) unsigned short Ps[4 * 16 * PS_LD];   // 21   KB
    unsigned short* Psw = &Ps[wid * 16 * PS_LD];

    // ---- stage K (row-major) and V (transposed), straight bf16 copies
    #pragma unroll
    for (int i = 0; i < 5; ++i) {
        int c = i * 256 + t;              // 0..1279 ushort8 slots
        int w = c >> 3, d8 = (c & 7) * 8;
        int r = t0 - 127 + w;
        r = min(max(r, 0), NTOK - 1);
        *(int4*)&Ks[w * KS_LD + d8] =
            *(const int4*)(qkvb + (size_t)r * QKV_N + KOFF + kh * DHEAD + d8);
        int4 vv = *(const int4*)(qkvb + (size_t)r * QKV_N + VOFF + kh * DHEAD + d8);
        const unsigned short* vp = (const unsigned short*)&vv;
        #pragma unroll
        for (int j = 0; j < 8; ++j) Vt[(d8 + j) * VT_LD + w] = vp[j];
    }
    __syncthreads();

    // ---- Q A-fragments straight from global bf16
    short8 qf[2][2];
    #pragma unroll
    for (int mt = 0; mt < 2; ++mt) {
        int m = wavebase + mt * 16 + ml;
        int tl = m & 15, g = m >> 4;
        const unsigned short* qp = qkvb + (size_t)(t0 + tl) * QKV_N + (kh * GQ + g) * DHEAD;
        #pragma unroll
        for (int kk = 0; kk < 2; ++kk)
            qf[mt][kk] = *(const short8*)(qp + kk * 32 + quad * 8);
    }

    // ---- S = Q K^T  (this wave: 2 m-tiles x 10 n-tiles)
    floatx4 S[2][10];
    #pragma unroll
    for (int mt = 0; mt < 2; ++mt)
        #pragma unroll
        for (int nt = 0; nt < 10; ++nt) S[mt][nt] = (floatx4){0.f, 0.f, 0.f, 0.f};
    #pragma unroll
    for (int kk = 0; kk < 2; ++kk) {
        #pragma unroll
        for (int nt = 0; nt < 10; ++nt) {
            short8 kb = *(const short8*)&Ks[(nt * 16 + ml) * KS_LD + kk * 32 + quad * 8];
            #pragma unroll
            for (int mt = 0; mt < 2; ++mt)
                S[mt][nt] = __builtin_amdgcn_mfma_f32_16x16x32_bf16(qf[mt][kk], kb, S[mt][nt], 0, 0, 0);
        }
    }

    // ---- band mask + scale   (valid: w>=tl, w<=tl+127, w>=127-t0)
    int wmin0 = 127 - t0;
    #pragma unroll
    for (int mt = 0; mt < 2; ++mt) {
        #pragma unroll
        for (int r = 0; r < 4; ++r) {
            int tl = (wavebase + mt * 16 + quad * 4 + r) & 15;
            int wlo = tl > wmin0 ? tl : wmin0;
            int whi = tl + 127;
            #pragma unroll
            for (int nt = 0; nt < 10; ++nt) {
                int w = nt * 16 + ml;
                float s = S[mt][nt][r] * 0.125f;
                S[mt][nt][r] = (w >= wlo && w <= whi) ? s : -INFINITY;
            }
        }
    }

    // ---- softmax with sink (rows spread over 16 lanes of the quad)
    #pragma unroll
    for (int mt = 0; mt < 2; ++mt) {
        int g = (wavebase + mt * 16) >> 4;
        float sk = sinks[kh * GQ + g];
        #pragma unroll
        for (int r = 0; r < 4; ++r) {
            float rm = -INFINITY;
            #pragma unroll
            for (int nt = 0; nt < 10; ++nt) rm = fmaxf(rm, S[mt][nt][r]);
            #pragma unroll
            for (int off = 1; off < 16; off <<= 1) rm = fmaxf(rm, __shfl_xor(rm, off));
            rm = fmaxf(rm, sk);
            float sum = 0.f;
            #pragma unroll
            for (int nt = 0; nt < 10; ++nt) {
                float p = __expf(S[mt][nt][r] - rm);   // exp(-inf)=0 masks
                S[mt][nt][r] = p;
                sum += p;
            }
            #pragma unroll
            for (int off = 1; off < 16; off <<= 1) sum += __shfl_xor(sum, off);
            float inv = 1.f / (sum + __expf(sk - rm));
            #pragma unroll
            for (int nt = 0; nt < 10; ++nt) S[mt][nt][r] *= inv;
        }
    }

    // ---- PV one m-tile at a time through per-wave Ps (wave DS ops in-order)
    #pragma unroll
    for (int mt = 0; mt < 2; ++mt) {
        #pragma unroll
        for (int r = 0; r < 4; ++r) {
            int lr = quad * 4 + r;
            #pragma unroll
            for (int nt = 0; nt < 10; ++nt)
                Psw[lr * PS_LD + nt * 16 + ml] = f2b(S[mt][nt][r]);
        }
        floatx4 O[4];
        #pragma unroll
        for (int j = 0; j < 4; ++j) O[j] = (floatx4){0.f, 0.f, 0.f, 0.f};
        #pragma unroll
        for (int ks = 0; ks < 5; ++ks) {
            short8 pf = *(const short8*)&Psw[ml * PS_LD + ks * 32 + quad * 8];
            #pragma unroll
            for (int nt = 0; nt < 4; ++nt) {
                short8 vf = *(const short8*)&Vt[(nt * 16 + ml) * VT_LD + ks * 32 + quad * 8];
                O[nt] = __builtin_amdgcn_mfma_f32_16x16x32_bf16(pf, vf, O[nt], 0, 0, 0);
            }
        }
        #pragma unroll
        for (int r = 0; r < 4; ++r) {
            int mm = wavebase + mt * 16 + quad * 4 + r;
            int tl = mm & 15, g = mm >> 4;
            unsigned short* op = aout + (size_t)(t0 + tl) * QCOLS + (kh * GQ + g) * DHEAD;
            #pragma unroll
            for (int nt = 0; nt < 4; ++nt)
                op[nt * 16 + ml] = f2b(O[nt][r]);
        }
    }
}

// ---------------------------------------------------------------------------
extern "C" void kernel_launch(void* const* d_in, const int* in_sizes, int n_in,
                              void* d_out, int out_size, void* d_ws, size_t ws_size,
                              hipStream_t stream) {
    const float* X     = (const float*)d_in[0];  // 1024x2880 f32
    const float* Wqkv  = (const float*)d_in[1];  // 2880x5120 f32
    const float* Wo    = (const float*)d_in[2];  // 4096x2880 f32
    const float* sinks = (const float*)d_in[3];  // 64 f32
    float* out = (float*)d_out;                  // 1024x2880 f32

    unsigned short *Xb, *qkvb, *attn, *WqkvT, *WoT;
    hipGetSymbolAddress((void**)&Xb,    HIP_SYMBOL(g_Xb));
    hipGetSymbolAddress((void**)&qkvb,  HIP_SYMBOL(g_qkvb));
    hipGetSymbolAddress((void**)&attn,  HIP_SYMBOL(g_attn));
    hipGetSymbolAddress((void**)&WqkvT, HIP_SYMBOL(g_WqkvT));
    hipGetSymbolAddress((void**)&WoT,   HIP_SYMBOL(g_WoT));

    cvt_bf16<<<(NTOK * HDIM / 4 + 255) / 256, 256, 0, stream>>>(X, Xb, NTOK * HDIM / 4);
    transpose_cvt<<<dim3(HDIM / 64, QKV_N / 64), 256, 0, stream>>>(Wqkv, WqkvT, HDIM, QKV_N);
    transpose_cvt<<<dim3(QCOLS / 64, HDIM / 64), 256, 0, stream>>>(Wo, WoT, QCOLS, HDIM);

    // QKV projection, direct full-K, fused RoPE -> bf16 qkv
    gemm_dir<HDIM, 0, QKV_N / 64><<<8 * (QKV_N / 64), 256, 0, stream>>>(Xb, WqkvT, qkvb);

    // MFMA sliding-window attention -> bf16 attn
    attn_mfma<<<512, 256, 0, stream>>>(qkvb, sinks, attn);

    // Output projection, direct full-K -> f32 out
    gemm_dir<QCOLS, 1, HDIM / 64><<<8 * (HDIM / 64), 256, 0, stream>>>(attn, WoT, out);
}

// Round 3
// 303.581 us; speedup vs baseline: 1.0892x; 1.0277x over previous
//
#include <hip/hip_runtime.h>
#include <hip/hip_bf16.h>

// Problem constants
#define HDIM   2880
#define NH     64
#define NKV    8
#define DHEAD  64
#define GQ     (NH / NKV)     // 8
#define WIN    128
#define NTOK   1024
#define QKV_N  ((NH + 2 * NKV) * DHEAD)   // 5120
#define QCOLS  (NH * DHEAD)               // 4096
#define KOFF   QCOLS                      // 4096
#define VOFF   (QCOLS + NKV * DHEAD)      // 4608

typedef __attribute__((ext_vector_type(8))) short short8;
typedef __attribute__((ext_vector_type(4))) float floatx4;

// Static device scratch (zero-init at module load).
__device__ unsigned short g_Xb   [(size_t)NTOK  * HDIM];          //  5.9 MB
__device__ unsigned short g_qkvb [(size_t)NTOK  * QKV_N];         // 10.5 MB bf16 qkv (post-rope)
__device__ unsigned short g_attn [(size_t)NTOK  * QCOLS];         //  8.4 MB
__device__ unsigned short g_WqkvT[(size_t)QKV_N * HDIM];          // 29.5 MB
__device__ unsigned short g_WoT  [(size_t)HDIM * QCOLS];          // 23.6 MB

__device__ __forceinline__ unsigned short f2b(float f) {
    __hip_bfloat16 h = __float2bfloat16(f);
    return *reinterpret_cast<unsigned short*>(&h);
}

__device__ __forceinline__ void gload_lds16(const unsigned short* g, unsigned short* l) {
    __builtin_amdgcn_global_load_lds(
        (const __attribute__((address_space(1))) unsigned int*)g,
        (__attribute__((address_space(3))) unsigned int*)l, 16, 0, 0);
}

// ---------------------------------------------------------------------------
// Fused transpose + f32->bf16 convert: in (K x N f32) -> out (N x K bf16).
// ---------------------------------------------------------------------------
__global__ __launch_bounds__(256) void transpose_cvt(
        const float* __restrict__ in, unsigned short* __restrict__ out,
        int K, int N) {
    int bk = blockIdx.x, bn = blockIdx.y;
    int t = threadIdx.x;
    __shared__ __align__(16) unsigned short T[64 * 72];
    #pragma unroll
    for (int i = 0; i < 4; ++i) {
        int c = i * 256 + t;          // float4 slots
        int r = c >> 4, cc = (c & 15) * 4;
        float4 v = *(const float4*)(in + (size_t)(bk * 64 + r) * N + bn * 64 + cc);
        T[r * 72 + cc + 0] = f2b(v.x);
        T[r * 72 + cc + 1] = f2b(v.y);
        T[r * 72 + cc + 2] = f2b(v.z);
        T[r * 72 + cc + 3] = f2b(v.w);
    }
    __syncthreads();
    #pragma unroll
    for (int i = 0; i < 2; ++i) {
        int c = i * 256 + t;
        int rn = c >> 3, kc = (c & 7) * 8;
        int4 vv;
        unsigned short* tp = (unsigned short*)&vv;
        #pragma unroll
        for (int j = 0; j < 8; ++j) tp[j] = T[(kc + j) * 72 + rn];
        *(int4*)(out + (size_t)(bn * 64 + rn) * K + bk * 64 + kc) = vv;
    }
}

// ---------------------------------------------------------------------------
// Elementwise f32 -> bf16 convert (for X).
// ---------------------------------------------------------------------------
__global__ __launch_bounds__(256) void cvt_bf16(
        const float* __restrict__ in, unsigned short* __restrict__ out, int n4) {
    int id = blockIdx.x * 256 + threadIdx.x;
    if (id >= n4) return;
    float4 v = *(const float4*)(in + (size_t)id * 4);
    ushort4 o;
    o.x = f2b(v.x); o.y = f2b(v.y); o.z = f2b(v.z); o.w = f2b(v.w);
    *(ushort4*)(out + (size_t)id * 4) = o;
}

// ---------------------------------------------------------------------------
// Direct full-K GEMM, 128x64 tile, BK=64, 4 waves stacked in M (each wave
// 32 rows x 64 cols, acc 2x4 of 16x16 frags).
// Depth-2 pipeline: 3 rotating LDS buffers, counted s_waitcnt vmcnt(6)
// (never 0 in the main loop) + raw s_barrier. Tile ti's loads are issued
// two compute-phases (~500 cy) ahead of use -> HBM latency off the
// critical path. WAR on buf[(ti+2)%3] is fenced by the barrier (it sits
// after all waves' compute(ti-1) reads of that buffer).
// LDS XOR-swizzle: 16B unit u of row r stored at u^(r&7) — applied by
// inverse-permuting the global SOURCE address (global_load_lds dest must
// stay linear) and permuting the ds_read address identically.
// XCD-aware bijective block swizzle (grid = 8*NBN, NBN col-tiles of 64).
// MODE 0: fused RoPE epilogue -> bf16 qkv (col tile == one head).
// MODE 1: plain f32 store to out (ld HDIM).
// ---------------------------------------------------------------------------
template<int KLEN, int MODE, int NBN>
__global__ __launch_bounds__(256) void gemm_dir(
        const unsigned short* __restrict__ A, const unsigned short* __restrict__ Bt,
        void* __restrict__ outp) {
    int d0 = blockIdx.x;                       // nwg = 8*NBN, nwg % 8 == 0
    int work = (d0 & 7) * NBN + (d0 >> 3);     // bijective XCD chunking
    int bm = work & 7, bn = work >> 3;         // 8 row tiles x NBN col tiles
    int t = threadIdx.x, lane = t & 63, wid = t >> 6;
    int quad = lane >> 4, ml = lane & 15;
    __shared__ __align__(16) unsigned short As[3][128 * 64];   // 3 x 16 KB
    __shared__ __align__(16) unsigned short Bs[3][64 * 64];    // 3 x  8 KB
    floatx4 acc[2][4];
    #pragma unroll
    for (int i = 0; i < 2; ++i)
        #pragma unroll
        for (int j = 0; j < 4; ++j) acc[i][j] = (floatx4){0.f, 0.f, 0.f, 0.f};

    int srow = lane >> 3;                      // 0..7 within an 8-row group
    int scol = ((lane & 7) ^ srow) * 8;        // inverse-swizzled source unit
    const unsigned short* Ab = A  + (size_t)(bm * 128) * KLEN;
    const unsigned short* Bb = Bt + (size_t)(bn * 64) * KLEN;

    constexpr int NT = KLEN / 64;

    auto STAGE = [&](int ti, int buf) {
        int k0 = ti * 64;
        #pragma unroll
        for (int j = 0; j < 4; ++j) {          // A: this wave's 4 groups
            int grp = wid * 4 + j;
            int r = grp * 8 + srow;
            gload_lds16(Ab + (size_t)r * KLEN + k0 + scol, &As[buf][grp * 512]);
        }
        #pragma unroll
        for (int j = 0; j < 2; ++j) {          // B: this wave's 2 groups
            int grp = wid * 2 + j;
            int r = grp * 8 + srow;
            gload_lds16(Bb + (size_t)r * KLEN + k0 + scol, &Bs[buf][grp * 512]);
        }
    };

    // prologue: tiles 0 and 1 in flight (12 loads/wave)
    STAGE(0, 0);
    STAGE(1, 1);

    for (int ti = 0; ti < NT; ++ti) {
        // wait for tile ti only (6 loads of tile ti+1 stay in flight)
        if (ti + 1 < NT) asm volatile("s_waitcnt vmcnt(6)" ::: "memory");
        else             asm volatile("s_waitcnt vmcnt(0)" ::: "memory");
        __builtin_amdgcn_s_barrier();
        if (ti + 2 < NT) STAGE(ti + 2, (ti + 2) % 3);
        int cur = ti % 3;
        #pragma unroll
        for (int kk = 0; kk < 64; kk += 32) {
            const int ub = kk >> 3;            // 0 or 4
            int usw = ((ub + quad) ^ (ml & 7)) * 8;
            short8 af[2], bf[4];
            #pragma unroll
            for (int mt = 0; mt < 2; ++mt)
                af[mt] = *(const short8*)&As[cur][(wid * 32 + mt * 16 + ml) * 64 + usw];
            #pragma unroll
            for (int nt = 0; nt < 4; ++nt)
                bf[nt] = *(const short8*)&Bs[cur][(nt * 16 + ml) * 64 + usw];
            #pragma unroll
            for (int mt = 0; mt < 2; ++mt)
                #pragma unroll
                for (int nt = 0; nt < 4; ++nt)
                    acc[mt][nt] = __builtin_amdgcn_mfma_f32_16x16x32_bf16(af[mt], bf[nt], acc[mt][nt], 0, 0, 0);
        }
    }

    if constexpr (MODE == 0) {
        // col tile bn == head bn; heads 0..71 are q/k (RoPE), 72..79 are v.
        unsigned short* qp = (unsigned short*)outp;
        int cb = bn * 64;
        if (bn < NH + NKV) {
            // inv_freq for this lane's two d values (d = ml, d = 16+ml)
            float inv0 = expf(-(float)ml * 0.3724497053f);          // theta^(-d/32)
            float inv1 = expf(-(float)(16 + ml) * 0.3724497053f);
            #pragma unroll
            for (int mt = 0; mt < 2; ++mt) {
                #pragma unroll
                for (int r = 0; r < 4; ++r) {
                    int n = bm * 128 + wid * 32 + mt * 16 + quad * 4 + r;
                    unsigned short* op = qp + (size_t)n * QKV_N + cb;
                    float s0, c0, s1, c1;
                    sincosf((float)n * inv0, &s0, &c0);
                    sincosf((float)n * inv1, &s1, &c1);
                    float x1a = acc[mt][0][r], x2a = acc[mt][2][r];
                    float x1b = acc[mt][1][r], x2b = acc[mt][3][r];
                    op[ml]           = f2b(x1a * c0 - x2a * s0);
                    op[ml + 32]      = f2b(x2a * c0 + x1a * s0);
                    op[16 + ml]      = f2b(x1b * c1 - x2b * s1);
                    op[16 + ml + 32] = f2b(x2b * c1 + x1b * s1);
                }
            }
        } else {
            #pragma unroll
            for (int mt = 0; mt < 2; ++mt)
                #pragma unroll
                for (int r = 0; r < 4; ++r) {
                    int n = bm * 128 + wid * 32 + mt * 16 + quad * 4 + r;
                    unsigned short* op = qp + (size_t)n * QKV_N + cb;
                    #pragma unroll
                    for (int nt = 0; nt < 4; ++nt)
                        op[nt * 16 + ml] = f2b(acc[mt][nt][r]);
                }
        }
    } else {
        float* op0 = (float*)outp;
        #pragma unroll
        for (int mt = 0; mt < 2; ++mt)
            #pragma unroll
            for (int r = 0; r < 4; ++r) {
                int n = bm * 128 + wid * 32 + mt * 16 + quad * 4 + r;
                float* op = op0 + (size_t)n * HDIM + bn * 64;
                #pragma unroll
                for (int nt = 0; nt < 4; ++nt)
                    op[nt * 16 + ml] = acc[mt][nt][r];
            }
    }
}

// ---------------------------------------------------------------------------
// MFMA flash-style sliding-window attention with sinks, bf16 in/out.
// 1D grid 512 with XCD swizzle: each XCD owns one kv-head (K/V L2-resident).
// Block = (16-token Q-tile, kv-head); M = 8 heads x 16 tokens = 128 rows;
// wave w owns rows [w*32, w*32+32). Window rows [t0-127, t0+32] staged.
// ---------------------------------------------------------------------------
#define TQ     16
#define WROWS  160
#define KS_LD  72
#define VT_LD  168
#define PS_LD  168

__global__ __launch_bounds__(256) void attn_mfma(
        const unsigned short* __restrict__ qkvb,
        const float* __restrict__ sinks,
        unsigned short* __restrict__ aout) {
    int d0 = blockIdx.x;                       // 512 blocks
    int work = (d0 & 7) * 64 + (d0 >> 3);      // bijective: XCD x -> kh == x
    int t0 = (work & 63) * TQ, kh = work >> 6;
    int t = threadIdx.x, lane = t & 63, wid = t >> 6;
    int quad = lane >> 4, ml = lane & 15;
    int wavebase = wid * 32;

    __shared__ __align__(16) unsigned short Ks[WROWS * KS_LD];    // 22.5 KB
    __shared__ __align__(16) unsigned short Vt[DHEAD * VT_LD];    // 21   KB
    __shared__ __align__(16) unsigned short Ps[4 * 16 * PS_LD];   // 21   KB
    unsigned short* Psw = &Ps[wid * 16 * PS_LD];

    // ---- stage K (row-major) and V (transposed), straight bf16 copies
    #pragma unroll
    for (int i = 0; i < 5; ++i) {
        int c = i * 256 + t;              // 0..1279 ushort8 slots
        int w = c >> 3, d8 = (c & 7) * 8;
        int r = t0 - 127 + w;
        r = min(max(r, 0), NTOK - 1);
        *(int4*)&Ks[w * KS_LD + d8] =
            *(const int4*)(qkvb + (size_t)r * QKV_N + KOFF + kh * DHEAD + d8);
        int4 vv = *(const int4*)(qkvb + (size_t)r * QKV_N + VOFF + kh * DHEAD + d8);
        const unsigned short* vp = (const unsigned short*)&vv;
        #pragma unroll
        for (int j = 0; j < 8; ++j) Vt[(d8 + j) * VT_LD + w] = vp[j];
    }
    __syncthreads();

    // ---- Q A-fragments straight from global bf16
    short8 qf[2][2];
    #pragma unroll
    for (int mt = 0; mt < 2; ++mt) {
        int m = wavebase + mt * 16 + ml;
        int tl = m & 15, g = m >> 4;
        const unsigned short* qp = qkvb + (size_t)(t0 + tl) * QKV_N + (kh * GQ + g) * DHEAD;
        #pragma unroll
        for (int kk = 0; kk < 2; ++kk)
            qf[mt][kk] = *(const short8*)(qp + kk * 32 + quad * 8);
    }

    // ---- S = Q K^T  (this wave: 2 m-tiles x 10 n-tiles)
    floatx4 S[2][10];
    #pragma unroll
    for (int mt = 0; mt < 2; ++mt)
        #pragma unroll
        for (int nt = 0; nt < 10; ++nt) S[mt][nt] = (floatx4){0.f, 0.f, 0.f, 0.f};
    #pragma unroll
    for (int kk = 0; kk < 2; ++kk) {
        #pragma unroll
        for (int nt = 0; nt < 10; ++nt) {
            short8 kb = *(const short8*)&Ks[(nt * 16 + ml) * KS_LD + kk * 32 + quad * 8];
            #pragma unroll
            for (int mt = 0; mt < 2; ++mt)
                S[mt][nt] = __builtin_amdgcn_mfma_f32_16x16x32_bf16(qf[mt][kk], kb, S[mt][nt], 0, 0, 0);
        }
    }

    // ---- band mask + scale   (valid: w>=tl, w<=tl+127, w>=127-t0)
    int wmin0 = 127 - t0;
    #pragma unroll
    for (int mt = 0; mt < 2; ++mt) {
        #pragma unroll
        for (int r = 0; r < 4; ++r) {
            int tl = (wavebase + mt * 16 + quad * 4 + r) & 15;
            int wlo = tl > wmin0 ? tl : wmin0;
            int whi = tl + 127;
            #pragma unroll
            for (int nt = 0; nt < 10; ++nt) {
                int w = nt * 16 + ml;
                float s = S[mt][nt][r] * 0.125f;
                S[mt][nt][r] = (w >= wlo && w <= whi) ? s : -INFINITY;
            }
        }
    }

    // ---- softmax with sink (rows spread over 16 lanes of the quad)
    #pragma unroll
    for (int mt = 0; mt < 2; ++mt) {
        int g = (wavebase + mt * 16) >> 4;
        float sk = sinks[kh * GQ + g];
        #pragma unroll
        for (int r = 0; r < 4; ++r) {
            float rm = -INFINITY;
            #pragma unroll
            for (int nt = 0; nt < 10; ++nt) rm = fmaxf(rm, S[mt][nt][r]);
            #pragma unroll
            for (int off = 1; off < 16; off <<= 1) rm = fmaxf(rm, __shfl_xor(rm, off));
            rm = fmaxf(rm, sk);
            float sum = 0.f;
            #pragma unroll
            for (int nt = 0; nt < 10; ++nt) {
                float p = __expf(S[mt][nt][r] - rm);   // exp(-inf)=0 masks
                S[mt][nt][r] = p;
                sum += p;
            }
            #pragma unroll
            for (int off = 1; off < 16; off <<= 1) sum += __shfl_xor(sum, off);
            float inv = 1.f / (sum + __expf(sk - rm));
            #pragma unroll
            for (int nt = 0; nt < 10; ++nt) S[mt][nt][r] *= inv;
        }
    }

    // ---- PV one m-tile at a time through per-wave Ps (wave DS ops in-order)
    #pragma unroll
    for (int mt = 0; mt < 2; ++mt) {
        #pragma unroll
        for (int r = 0; r < 4; ++r) {
            int lr = quad * 4 + r;
            #pragma unroll
            for (int nt = 0; nt < 10; ++nt)
                Psw[lr * PS_LD + nt * 16 + ml] = f2b(S[mt][nt][r]);
        }
        floatx4 O[4];
        #pragma unroll
        for (int j = 0; j < 4; ++j) O[j] = (floatx4){0.f, 0.f, 0.f, 0.f};
        #pragma unroll
        for (int ks = 0; ks < 5; ++ks) {
            short8 pf = *(const short8*)&Psw[ml * PS_LD + ks * 32 + quad * 8];
            #pragma unroll
            for (int nt = 0; nt < 4; ++nt) {
                short8 vf = *(const short8*)&Vt[(nt * 16 + ml) * VT_LD + ks * 32 + quad * 8];
                O[nt] = __builtin_amdgcn_mfma_f32_16x16x32_bf16(pf, vf, O[nt], 0, 0, 0);
            }
        }
        #pragma unroll
        for (int r = 0; r < 4; ++r) {
            int mm = wavebase + mt * 16 + quad * 4 + r;
            int tl = mm & 15, g = mm >> 4;
            unsigned short* op = aout + (size_t)(t0 + tl) * QCOLS + (kh * GQ + g) * DHEAD;
            #pragma unroll
            for (int nt = 0; nt < 4; ++nt)
                op[nt * 16 + ml] = f2b(O[nt][r]);
        }
    }
}

// ---------------------------------------------------------------------------
extern "C" void kernel_launch(void* const* d_in, const int* in_sizes, int n_in,
                              void* d_out, int out_size, void* d_ws, size_t ws_size,
                              hipStream_t stream) {
    const float* X     = (const float*)d_in[0];  // 1024x2880 f32
    const float* Wqkv  = (const float*)d_in[1];  // 2880x5120 f32
    const float* Wo    = (const float*)d_in[2];  // 4096x2880 f32
    const float* sinks = (const float*)d_in[3];  // 64 f32
    float* out = (float*)d_out;                  // 1024x2880 f32

    unsigned short *Xb, *qkvb, *attn, *WqkvT, *WoT;
    hipGetSymbolAddress((void**)&Xb,    HIP_SYMBOL(g_Xb));
    hipGetSymbolAddress((void**)&qkvb,  HIP_SYMBOL(g_qkvb));
    hipGetSymbolAddress((void**)&attn,  HIP_SYMBOL(g_attn));
    hipGetSymbolAddress((void**)&WqkvT, HIP_SYMBOL(g_WqkvT));
    hipGetSymbolAddress((void**)&WoT,   HIP_SYMBOL(g_WoT));

    cvt_bf16<<<(NTOK * HDIM / 4 + 255) / 256, 256, 0, stream>>>(X, Xb, NTOK * HDIM / 4);
    transpose_cvt<<<dim3(HDIM / 64, QKV_N / 64), 256, 0, stream>>>(Wqkv, WqkvT, HDIM, QKV_N);
    transpose_cvt<<<dim3(QCOLS / 64, HDIM / 64), 256, 0, stream>>>(Wo, WoT, QCOLS, HDIM);

    // QKV projection, direct full-K, fused RoPE -> bf16 qkv
    gemm_dir<HDIM, 0, QKV_N / 64><<<8 * (QKV_N / 64), 256, 0, stream>>>(Xb, WqkvT, qkvb);

    // MFMA sliding-window attention -> bf16 attn
    attn_mfma<<<512, 256, 0, stream>>>(qkvb, sinks, attn);

    // Output projection, direct full-K -> f32 out
    gemm_dir<QCOLS, 1, HDIM / 64><<<8 * (HDIM / 64), 256, 0, stream>>>(attn, WoT, out);
}